// Round 7
// baseline (282.569 us; speedup 1.0000x reference)
//
#include <hip/hip_runtime.h>
#include <hip/hip_bf16.h>

#define BB 8192
#define SS 20
#define DD 300
#define JJ 512
#define NII 1000
#define VGG 2078
#define KP 328           // k2 K padded: cols 0-299 W_sent, 300=b_sent, 301=b_emb, rest 0
#define RBY 656          // A-stage LDS / Wsb global row bytes
#define BTILE 41984      // 64 * 656 bytes per jt column-tile of Wsb
#define FLP 516          // femb LDS row stride (floats)
#define BP1 72           // k1 64x64 chunk lds row stride

typedef __attribute__((ext_vector_type(8))) short short8v;
typedef __attribute__((ext_vector_type(4))) float float4v;

__device__ __forceinline__ unsigned short bf16u(float x) {
    __hip_bfloat16 h = __float2bfloat16(x);
    return *(unsigned short*)&h;
}
__device__ __forceinline__ float bfraw2f(unsigned short u) {
    return __uint_as_float((unsigned)u << 16);
}

// ---------------- pad+convert fp32 -> bf16 with zero pad on cols ----------------
__global__ __launch_bounds__(256) void kc_pad_bf16(const float* __restrict__ src,
                                                   __hip_bfloat16* __restrict__ dst,
                                                   int rows, int scols, int dcols) {
    int idx = blockIdx.x * 256 + threadIdx.x;
    if (idx >= rows * dcols) return;
    int r = idx / dcols, c = idx % dcols;
    float v = (c < scols) ? src[(long)r * scols + c] : 0.f;
    dst[idx] = __float2bfloat16(v);
}

// ---------------- Wsb prep: [512][328] with bias columns folded in -------------
__global__ __launch_bounds__(256) void kc_prep_wsb(const float* __restrict__ W_sent,
                                                   const float* __restrict__ b_sent,
                                                   const float* __restrict__ b_emb,
                                                   __hip_bfloat16* __restrict__ dst) {
    int idx = blockIdx.x * 256 + threadIdx.x;
    if (idx >= JJ * KP) return;
    int j = idx / KP, c = idx % KP;
    float v = (c < DD) ? W_sent[(long)j * DD + c]
            : (c == DD) ? b_sent[j]
            : (c == DD + 1) ? b_emb[j] : 0.f;
    dst[idx] = __float2bfloat16(v);
}

// ---------------- sum of w_fc (one block) --------------------------------------
__global__ __launch_bounds__(512) void kS_sumwf(const float* __restrict__ w_fc,
                                                float* __restrict__ out) {
    __shared__ float part[8];
    int t = threadIdx.x;
    float v = w_fc[t];
    v += __shfl_xor(v, 1);  v += __shfl_xor(v, 2);  v += __shfl_xor(v, 4);
    v += __shfl_xor(v, 8);  v += __shfl_xor(v, 16); v += __shfl_xor(v, 32);
    if ((t & 63) == 0) part[t >> 6] = v;
    __syncthreads();
    if (t == 0) {
        float s = 0.f;
#pragma unroll
        for (int i = 0; i < 8; ++i) s += part[i];
        out[0] = s;
    }
}

// ---------------- kernel 0: valid / nonzero masks ----------------
__global__ __launch_bounds__(256) void k0_valid(const int* __restrict__ labels,
                                                float* __restrict__ valid,
                                                float* __restrict__ nonzero) {
    int b = blockIdx.x * blockDim.x + threadIdx.x;
    if (b >= BB) return;
    float v = 1.f;
    for (int s = 0; s < SS; ++s) {
        float nz = (labels[b * SS + s] != 0) ? 1.f : 0.f;
        v *= nz;
        nonzero[b * SS + s] = nz;
        valid[b * SS + s] = v;
    }
}

// ---------------- kernel 1 (MFMA): femb = bf16(guide @ W_emb^T + b_emb) --------
__global__ __launch_bounds__(256) void k1_femb_mfma(
    const __hip_bfloat16* __restrict__ Gb,   // [NII][2112]
    const __hip_bfloat16* __restrict__ Web,  // [JJ][2112]
    const float* __restrict__ b_emb,
    __hip_bfloat16* __restrict__ femb) {     // [1024][JJ]
    __shared__ __hip_bfloat16 Al[64 * BP1];
    __shared__ __hip_bfloat16 Bl[64 * BP1];
    const int t = threadIdx.x;
    const int m0 = blockIdx.x * 64;
    const int n0 = blockIdx.y * 64;
    const int lane = t & 63;
    const int w = t >> 6;
    const int wm = w >> 1, wn = w & 1;
    const int li = lane & 15, lq = lane >> 4;

    float4v acc[2][2] = {};

    for (int kt = 0; kt < 33; ++kt) {
        for (int c = t; c < 512; c += 256) {
            int rr = c >> 3, off = (c & 7) * 8;
            int gr = m0 + rr; if (gr > NII - 1) gr = NII - 1;
            *(uint4*)&Al[rr * BP1 + off] =
                *(const uint4*)(Gb + (long)gr * 2112 + kt * 64 + off);
            *(uint4*)&Bl[rr * BP1 + off] =
                *(const uint4*)(Web + (long)(n0 + rr) * 2112 + kt * 64 + off);
        }
        __syncthreads();
#pragma unroll
        for (int ks = 0; ks < 2; ++ks) {
            short8v a[2], b[2];
#pragma unroll
            for (int mt = 0; mt < 2; ++mt)
                a[mt] = *(const short8v*)&Al[(wm * 32 + mt * 16 + li) * BP1 + ks * 32 + lq * 8];
#pragma unroll
            for (int nt = 0; nt < 2; ++nt)
                b[nt] = *(const short8v*)&Bl[(wn * 32 + nt * 16 + li) * BP1 + ks * 32 + lq * 8];
#pragma unroll
            for (int mt = 0; mt < 2; ++mt)
#pragma unroll
                for (int nt = 0; nt < 2; ++nt)
                    acc[mt][nt] = __builtin_amdgcn_mfma_f32_16x16x32_bf16(
                        a[mt], b[nt], acc[mt][nt], 0, 0, 0);
        }
        __syncthreads();
    }
#pragma unroll
    for (int nt = 0; nt < 2; ++nt) {
        int col = n0 + wn * 32 + nt * 16 + li;
        float be = b_emb[col];
#pragma unroll
        for (int mt = 0; mt < 2; ++mt)
#pragma unroll
            for (int reg = 0; reg < 4; ++reg) {
                int row = wm * 32 + mt * 16 + lq * 4 + reg;
                femb[(long)(m0 + row) * JJ + col] = __float2bfloat16(acc[mt][nt][reg] + be);
            }
    }
}

// ---------------- kernel 2 (MFMA): fused scores -------------------------------
// BM=64, 4 waves (2m x 2n). A (incl folded bias cols) staged once -> areg[2][10].
// B fragments read DIRECTLY from global Wsb (L2-resident, 336KB): no LDS B tile,
// no per-jt barriers, no vmcnt(0) drains. Epilogue: x = acc + vm*femb;
// score = b_fc + sum(w_fc) - 2*sum(w_fc / (exp(2x)+1)).
// LDS 52304 B -> 3 blocks/CU; no launch_bounds cap (avoid round-4 spills).
__global__ __launch_bounds__(256) void k2_scores_mfma(
    const float* __restrict__ context,
    const __hip_bfloat16* __restrict__ Wsb,  // [JJ][KP] with bias cols
    const float* __restrict__ w_fc,
    const float* __restrict__ b_fc,
    const float* __restrict__ sumwf,
    const __hip_bfloat16* __restrict__ femb, // [1024][JJ]
    const int* __restrict__ ann,
    const float* __restrict__ valid,
    float* __restrict__ scores) {
    __shared__ __align__(16) char smem[41984 + 5 * FLP * 4];
    char* buf = smem;                        // A-stage [64][328] bf16
    float* fl = (float*)(smem + 41984);      // femb rows, f32 [5][FLP]

    const int t = threadIdx.x;
    const int m0 = blockIdx.x * 64;
    const int b_lo = m0 / SS;
    const int lane = t & 63;
    const int w = t >> 6;
    const int wm = w >> 1, wn = w & 1;
    const int li = lane & 15, lq = lane >> 4;

    // ---- stage A: context -> bf16; col300=1.0, col301=1-valid, col>=302 = 0 ----
    for (int idx = t; idx < 64 * 82; idx += 256) {
        int r = idx / 82, q = idx - r * 82;
        ushort4 pk;
        if (q < 75) {
            float4 v = *(const float4*)(context + (long)(m0 + r) * DD + q * 4);
            pk.x = bf16u(v.x); pk.y = bf16u(v.y); pk.z = bf16u(v.z); pk.w = bf16u(v.w);
        } else if (q == 75) {
            pk.x = bf16u(1.f); pk.y = bf16u(1.f - valid[m0 + r]); pk.z = 0; pk.w = 0;
        } else { pk.x = pk.y = pk.z = pk.w = 0; }
        *(ushort4*)(buf + r * RBY + q * 8) = pk;
    }
    // ---- stage femb rows (<=5 distinct b) as f32 ----
    if (t < 320) {
        int i = t >> 6, ch = t & 63;
        int b = b_lo + i; if (b > BB - 1) b = BB - 1;
        int grow = ann[2 * b];
        short8v rv = *(const short8v*)(femb + (long)grow * JJ + ch * 8);
        float4 lo, hi;
        lo.x = bfraw2f((unsigned short)rv[0]); lo.y = bfraw2f((unsigned short)rv[1]);
        lo.z = bfraw2f((unsigned short)rv[2]); lo.w = bfraw2f((unsigned short)rv[3]);
        hi.x = bfraw2f((unsigned short)rv[4]); hi.y = bfraw2f((unsigned short)rv[5]);
        hi.z = bfraw2f((unsigned short)rv[6]); hi.w = bfraw2f((unsigned short)rv[7]);
        *(float4*)(fl + i * FLP + ch * 8)     = lo;
        *(float4*)(fl + i * FLP + ch * 8 + 4) = hi;
    }
    // ---- per-row-slot metadata ----
    float vm[8]; int selb = 0; int br_[2];
#pragma unroll
    for (int mt = 0; mt < 2; ++mt) {
        int base = m0 + wm * 32 + mt * 16 + lq * 4;
        int br0 = base / SS - b_lo;
        br_[mt] = br0;
#pragma unroll
        for (int reg = 0; reg < 4; ++reg) {
            int m = base + reg;
            int slot = mt * 4 + reg;
            if (m / SS - b_lo != br0) selb |= (1 << slot);
            vm[slot] = valid[m];
        }
    }
    __syncthreads();

    // ---- A fragments -> registers (80 VGPR) ----
    short8v areg[2][10];
#pragma unroll
    for (int mt = 0; mt < 2; ++mt) {
        int r = wm * 32 + mt * 16 + li;
#pragma unroll
        for (int kt = 0; kt < 10; ++kt)
            areg[mt][kt] = *(const short8v*)(buf + r * RBY + kt * 64 + lq * 16);
    }

    float sp2[8] = {0.f, 0.f, 0.f, 0.f, 0.f, 0.f, 0.f, 0.f};
    const char* pB = (const char*)Wsb + (wn * 32 + li) * RBY + lq * 16;

    for (int jt = 0; jt < 8; ++jt) {
        const char* pj = pB + (long)jt * BTILE;
        float4v acc[2][2] = {};
        short8v bf0[5], bf1[5];
        // K half 1 (k 0..159)
#pragma unroll
        for (int kt = 0; kt < 5; ++kt) {
            bf0[kt] = *(const short8v*)(pj + kt * 64);
            bf1[kt] = *(const short8v*)(pj + 16 * RBY + kt * 64);
        }
#pragma unroll
        for (int kt = 0; kt < 5; ++kt) {
            acc[0][0] = __builtin_amdgcn_mfma_f32_16x16x32_bf16(areg[0][kt], bf0[kt], acc[0][0], 0, 0, 0);
            acc[0][1] = __builtin_amdgcn_mfma_f32_16x16x32_bf16(areg[0][kt], bf1[kt], acc[0][1], 0, 0, 0);
            acc[1][0] = __builtin_amdgcn_mfma_f32_16x16x32_bf16(areg[1][kt], bf0[kt], acc[1][0], 0, 0, 0);
            acc[1][1] = __builtin_amdgcn_mfma_f32_16x16x32_bf16(areg[1][kt], bf1[kt], acc[1][1], 0, 0, 0);
        }
        // K half 2 (k 160..319; includes folded bias cols 300/301)
#pragma unroll
        for (int kt = 0; kt < 5; ++kt) {
            bf0[kt] = *(const short8v*)(pj + 320 + kt * 64);
            bf1[kt] = *(const short8v*)(pj + 16 * RBY + 320 + kt * 64);
        }
#pragma unroll
        for (int kt = 0; kt < 5; ++kt) {
            acc[0][0] = __builtin_amdgcn_mfma_f32_16x16x32_bf16(areg[0][5 + kt], bf0[kt], acc[0][0], 0, 0, 0);
            acc[0][1] = __builtin_amdgcn_mfma_f32_16x16x32_bf16(areg[0][5 + kt], bf1[kt], acc[0][1], 0, 0, 0);
            acc[1][0] = __builtin_amdgcn_mfma_f32_16x16x32_bf16(areg[1][5 + kt], bf0[kt], acc[1][0], 0, 0, 0);
            acc[1][1] = __builtin_amdgcn_mfma_f32_16x16x32_bf16(areg[1][5 + kt], bf1[kt], acc[1][1], 0, 0, 0);
        }
        // ---- epilogue: sp2 += w_fc / (exp(2x)+1), x = acc + vm*femb ----
#pragma unroll
        for (int nt = 0; nt < 2; ++nt) {
            int col = jt * 64 + wn * 32 + nt * 16 + li;
            float wf = w_fc[col];
#pragma unroll
            for (int mt = 0; mt < 2; ++mt) {
                int br = br_[mt];
                int br1 = (br < 4) ? br + 1 : 4;
                float f0 = fl[br * FLP + col];
                float f1 = fl[br1 * FLP + col];
#pragma unroll
                for (int reg = 0; reg < 4; ++reg) {
                    int slot = mt * 4 + reg;
                    float fv = ((selb >> slot) & 1) ? f1 : f0;
                    float x = acc[mt][nt][reg] + vm[slot] * fv;
                    float e = __expf(2.f * x);
                    float r = __builtin_amdgcn_rcpf(e + 1.f);
                    sp2[slot] += wf * r;
                }
            }
        }
    }

    // reduce across the 16 li lanes per row-slot
#pragma unroll
    for (int slot = 0; slot < 8; ++slot) {
        float v = sp2[slot];
        v += __shfl_xor(v, 1); v += __shfl_xor(v, 2);
        v += __shfl_xor(v, 4); v += __shfl_xor(v, 8);
        sp2[slot] = v;
    }
    __syncthreads();               // all waves done with buf/fl
    float* red = (float*)smem;
    if (li == 0) {
#pragma unroll
        for (int mt = 0; mt < 2; ++mt)
#pragma unroll
            for (int reg = 0; reg < 4; ++reg)
                red[wn * 64 + wm * 32 + mt * 16 + lq * 4 + reg] = sp2[mt * 4 + reg];
    }
    __syncthreads();
    if (t < 64)
        scores[m0 + t] = b_fc[0] + sumwf[0] - 2.f * (red[t] + red[64 + t]);
}

// ---------------- kernel 3: softmax + mask + renorm + weighted sum -------------
__global__ __launch_bounds__(256) void k3_out(const float* __restrict__ scores,
                                              const float* __restrict__ nonzero,
                                              const float* __restrict__ embedded,
                                              float* __restrict__ out) {
    __shared__ float wgt[3][SS];
    const int b0 = blockIdx.x * 3;
    const int t = threadIdx.x;
    if (t < 3) {
        int b = b0 + t;
        if (b < BB) {
            float sc[SS], nz[SS];
            float mx = -1e30f;
            for (int s = 0; s < SS; ++s) {
                sc[s] = scores[b * SS + s];
                nz[s] = nonzero[b * SS + s];
                mx = fmaxf(mx, sc[s]);
            }
            float den = 0.f, e[SS];
            for (int s = 0; s < SS; ++s) { e[s] = nz[s] * __expf(sc[s] - mx); den += e[s]; }
            float inv = 1.f / den;
            for (int s = 0; s < SS; ++s) wgt[t][s] = e[s] * inv;
        }
    }
    __syncthreads();
    if (t < 225) {
        int r = t / 75, q = t - r * 75;
        int b = b0 + r;
        if (b < BB) {
            float4 a; a.x = a.y = a.z = a.w = 0.f;
#pragma unroll
            for (int s = 0; s < SS; ++s) {
                float4 e = *(const float4*)(embedded + ((long)b * SS + s) * DD + q * 4);
                float ww = wgt[r][s];
                a.x += ww * e.x; a.y += ww * e.y; a.z += ww * e.z; a.w += ww * e.w;
            }
            *(float4*)(out + (long)b * DD + q * 4) = a;
        }
    }
}

extern "C" void kernel_launch(void* const* d_in, const int* in_sizes, int n_in,
                              void* d_out, int out_size, void* d_ws, size_t ws_size,
                              hipStream_t stream) {
    const float* context  = (const float*)d_in[0];
    const float* embedded = (const float*)d_in[1];
    const int*   labels   = (const int*)d_in[2];
    const float* guide    = (const float*)d_in[3];
    const int*   ann      = (const int*)d_in[4];
    const float* W_sent   = (const float*)d_in[5];
    const float* b_sent   = (const float*)d_in[6];
    const float* W_emb    = (const float*)d_in[7];
    const float* b_emb    = (const float*)d_in[8];
    const float* w_fc     = (const float*)d_in[9];
    const float* b_fc     = (const float*)d_in[10];
    float* out = (float*)d_out;

    char* w = (char*)d_ws;
    __hip_bfloat16* femb = (__hip_bfloat16*)(w);               // 1024*512*2 = 1048576
    float* valid         = (float*)(w + 1048576);              // 655360
    float* nonzero       = (float*)(w + 1703936);              // 655360
    float* scores        = (float*)(w + 2359296);              // 655360
    __hip_bfloat16* Wsb  = (__hip_bfloat16*)(w + 3014656);     // 512*328*2 = 335872
    __hip_bfloat16* Web  = (__hip_bfloat16*)(w + 3350528);     // 512*2112*2= 2162688
    __hip_bfloat16* Gb   = (__hip_bfloat16*)(w + 5513216);     // 1000*2112*2=4224000
    float* sums          = (float*)(w + 9737216);              // 4
    // total 9737220 bytes

    hipLaunchKernelGGL(kc_prep_wsb, dim3((JJ * KP + 255) / 256), dim3(256), 0, stream,
                       W_sent, b_sent, b_emb, Wsb);
    hipLaunchKernelGGL(kc_pad_bf16, dim3((JJ * 2112 + 255) / 256), dim3(256), 0, stream,
                       W_emb, Web, JJ, VGG, 2112);
    hipLaunchKernelGGL(kc_pad_bf16, dim3((NII * 2112 + 255) / 256), dim3(256), 0, stream,
                       guide, Gb, NII, VGG, 2112);
    hipLaunchKernelGGL(kS_sumwf, dim3(1), dim3(512), 0, stream, w_fc, sums);
    hipLaunchKernelGGL(k0_valid, dim3(BB / 256), dim3(256), 0, stream,
                       labels, valid, nonzero);
    hipLaunchKernelGGL(k1_femb_mfma, dim3(16, JJ / 64), dim3(256), 0, stream,
                       Gb, Web, b_emb, femb);
    hipLaunchKernelGGL(k2_scores_mfma, dim3((BB * SS) / 64), dim3(256), 0, stream,
                       context, Wsb, w_fc, b_fc, sums, femb, ann, valid, scores);
    hipLaunchKernelGGL(k3_out, dim3((BB + 2) / 3), dim3(256), 0, stream,
                       scores, nonzero, embedded, out);
}

// Round 8
// 267.340 us; speedup vs baseline: 1.0570x; 1.0570x over previous
//
#include <hip/hip_runtime.h>
#include <hip/hip_bf16.h>

#define BB 8192
#define SS 20
#define DD 300
#define JJ 512
#define NII 1000
#define VGG 2078
#define KP 328           // k2 K padded: cols 0-299 W_sent, 300=b_sent, 301=b_emb, rest 0
#define RBY 656          // A-stage LDS / Wsb global row bytes
#define BT2 20992        // 32 * 656: one jt B tile (contiguous in global)
#define BP1 72           // k1 64x64 chunk lds row stride

typedef __attribute__((ext_vector_type(8))) short short8v;
typedef __attribute__((ext_vector_type(4))) float float4v;

__device__ __forceinline__ unsigned short bf16u(float x) {
    __hip_bfloat16 h = __float2bfloat16(x);
    return *(unsigned short*)&h;
}
__device__ __forceinline__ float bfraw2f(unsigned short u) {
    return __uint_as_float((unsigned)u << 16);
}
// async global->LDS, 16B per lane; LDS dest = wave-uniform base + lane*16
__device__ __forceinline__ void gload16(const void* g, void* l) {
    __builtin_amdgcn_global_load_lds(
        (const __attribute__((address_space(1))) unsigned int*)g,
        (__attribute__((address_space(3))) unsigned int*)l, 16, 0, 0);
}

// ---------------- combined pad+convert for W_emb (512 rows) + guide (1000 rows) -
__global__ __launch_bounds__(256) void kc_pad2(const float* __restrict__ W_emb,
                                               const float* __restrict__ guide,
                                               __hip_bfloat16* __restrict__ Web,
                                               __hip_bfloat16* __restrict__ Gb) {
    long idx = (long)blockIdx.x * 256 + threadIdx.x;
    if (idx >= 1512L * 2112) return;
    int r = (int)(idx / 2112), c = (int)(idx % 2112);
    if (r < JJ) {
        float v = (c < VGG) ? W_emb[(long)r * VGG + c] : 0.f;
        Web[(long)r * 2112 + c] = __float2bfloat16(v);
    } else {
        int g = r - JJ;
        float v = (c < VGG) ? guide[(long)g * VGG + c] : 0.f;
        Gb[(long)g * 2112 + c] = __float2bfloat16(v);
    }
}

// ---------------- Wsb prep: [512][328] with bias columns folded in -------------
__global__ __launch_bounds__(256) void kc_prep_wsb(const float* __restrict__ W_sent,
                                                   const float* __restrict__ b_sent,
                                                   const float* __restrict__ b_emb,
                                                   __hip_bfloat16* __restrict__ dst) {
    int idx = blockIdx.x * 256 + threadIdx.x;
    if (idx >= JJ * KP) return;
    int j = idx / KP, c = idx % KP;
    float v = (c < DD) ? W_sent[(long)j * DD + c]
            : (c == DD) ? b_sent[j]
            : (c == DD + 1) ? b_emb[j] : 0.f;
    dst[idx] = __float2bfloat16(v);
}

// ---------------- sum of w_fc (one block) --------------------------------------
__global__ __launch_bounds__(512) void kS_sumwf(const float* __restrict__ w_fc,
                                                float* __restrict__ out) {
    __shared__ float part[8];
    int t = threadIdx.x;
    float v = w_fc[t];
    v += __shfl_xor(v, 1);  v += __shfl_xor(v, 2);  v += __shfl_xor(v, 4);
    v += __shfl_xor(v, 8);  v += __shfl_xor(v, 16); v += __shfl_xor(v, 32);
    if ((t & 63) == 0) part[t >> 6] = v;
    __syncthreads();
    if (t == 0) {
        float s = 0.f;
#pragma unroll
        for (int i = 0; i < 8; ++i) s += part[i];
        out[0] = s;
    }
}

// ---------------- kernel 0: valid / nonzero masks ----------------
__global__ __launch_bounds__(256) void k0_valid(const int* __restrict__ labels,
                                                float* __restrict__ valid,
                                                float* __restrict__ nonzero) {
    int b = blockIdx.x * blockDim.x + threadIdx.x;
    if (b >= BB) return;
    float v = 1.f;
    for (int s = 0; s < SS; ++s) {
        float nz = (labels[b * SS + s] != 0) ? 1.f : 0.f;
        v *= nz;
        nonzero[b * SS + s] = nz;
        valid[b * SS + s] = v;
    }
}

// ---------------- kernel 1 (MFMA): femb = bf16(guide @ W_emb^T + b_emb) --------
__global__ __launch_bounds__(256) void k1_femb_mfma(
    const __hip_bfloat16* __restrict__ Gb,   // [NII][2112]
    const __hip_bfloat16* __restrict__ Web,  // [JJ][2112]
    const float* __restrict__ b_emb,
    __hip_bfloat16* __restrict__ femb) {     // [1024][JJ]
    __shared__ __hip_bfloat16 Al[64 * BP1];
    __shared__ __hip_bfloat16 Bl[64 * BP1];
    const int t = threadIdx.x;
    const int m0 = blockIdx.x * 64;
    const int n0 = blockIdx.y * 64;
    const int lane = t & 63;
    const int w = t >> 6;
    const int wm = w >> 1, wn = w & 1;
    const int li = lane & 15, lq = lane >> 4;

    float4v acc[2][2] = {};

    for (int kt = 0; kt < 33; ++kt) {
        for (int c = t; c < 512; c += 256) {
            int rr = c >> 3, off = (c & 7) * 8;
            int gr = m0 + rr; if (gr > NII - 1) gr = NII - 1;
            *(uint4*)&Al[rr * BP1 + off] =
                *(const uint4*)(Gb + (long)gr * 2112 + kt * 64 + off);
            *(uint4*)&Bl[rr * BP1 + off] =
                *(const uint4*)(Web + (long)(n0 + rr) * 2112 + kt * 64 + off);
        }
        __syncthreads();
#pragma unroll
        for (int ks = 0; ks < 2; ++ks) {
            short8v a[2], b[2];
#pragma unroll
            for (int mt = 0; mt < 2; ++mt)
                a[mt] = *(const short8v*)&Al[(wm * 32 + mt * 16 + li) * BP1 + ks * 32 + lq * 8];
#pragma unroll
            for (int nt = 0; nt < 2; ++nt)
                b[nt] = *(const short8v*)&Bl[(wn * 32 + nt * 16 + li) * BP1 + ks * 32 + lq * 8];
#pragma unroll
            for (int mt = 0; mt < 2; ++mt)
#pragma unroll
                for (int nt = 0; nt < 2; ++nt)
                    acc[mt][nt] = __builtin_amdgcn_mfma_f32_16x16x32_bf16(
                        a[mt], b[nt], acc[mt][nt], 0, 0, 0);
        }
        __syncthreads();
    }
#pragma unroll
    for (int nt = 0; nt < 2; ++nt) {
        int col = n0 + wn * 32 + nt * 16 + li;
        float be = b_emb[col];
#pragma unroll
        for (int mt = 0; mt < 2; ++mt)
#pragma unroll
            for (int reg = 0; reg < 4; ++reg) {
                int row = wm * 32 + mt * 16 + lq * 4 + reg;
                femb[(long)(m0 + row) * JJ + col] = __float2bfloat16(acc[mt][nt][reg] + be);
            }
    }
}

// ---------------- kernel 2 (MFMA): fused scores -------------------------------
// BM=64 rows, 4 waves (2m x 2n), per-wave 32r x 16c per jt tile. 16 jt tiles of
// BN=32. A (incl folded bias cols 300/301) staged once -> areg[2][10] (regs).
// B: double-buffered in the SAME LDS region as the A-stage (2 x 20992 = 41984),
// staged via global_load_lds, prefetch of jt+1 issued BEFORE compute of jt,
// ONE barrier per jt (2-phase pipeline). Epilogue: x = acc + vm*femb;
// score = b_fc + sum(w_fc) - 2*sum(w_fc * rcp(exp(2x)+1)).
// LDS 54272 -> 3 blocks/CU; no waves-per-EU cap (round-4 spill lesson).
__global__ __launch_bounds__(256) void k2_scores_mfma(
    const float* __restrict__ context,
    const __hip_bfloat16* __restrict__ Wsb,  // [JJ][KP] with bias cols
    const float* __restrict__ w_fc,
    const float* __restrict__ b_fc,
    const float* __restrict__ sumwf,
    const __hip_bfloat16* __restrict__ femb, // [1024][JJ]
    const int* __restrict__ ann,
    const float* __restrict__ valid,
    float* __restrict__ scores) {
    __shared__ __align__(16) char smem[54272];
    char* buf  = smem;                       // A-stage [64][656B]  /  B dbuf 2x20992
    float* fl  = (float*)(smem + 41984);     // femb f32 [5][512] = 10240
    float* wl  = (float*)(smem + 52224);     // w_fc [512] = 2048

    const int t = threadIdx.x;
    const int m0 = blockIdx.x * 64;
    const int b_lo = m0 / SS;
    const int lane = t & 63;
    const int w = t >> 6;
    const int wm = w >> 1, wn = w & 1;
    const int li = lane & 15, lq = lane >> 4;

    // ---- stage A: context -> bf16; col300=1.0, col301=1-valid, col>=302=0 ----
    for (int idx = t; idx < 64 * 82; idx += 256) {
        int r = idx / 82, q = idx - r * 82;
        ushort4 pk;
        if (q < 75) {
            float4 v = *(const float4*)(context + (long)(m0 + r) * DD + q * 4);
            pk.x = bf16u(v.x); pk.y = bf16u(v.y); pk.z = bf16u(v.z); pk.w = bf16u(v.w);
        } else if (q == 75) {
            pk.x = bf16u(1.f); pk.y = bf16u(1.f - valid[m0 + r]); pk.z = 0; pk.w = 0;
        } else { pk.x = pk.y = pk.z = pk.w = 0; }
        *(ushort4*)(buf + r * RBY + q * 8) = pk;
    }
    // ---- stage femb rows (<=5 distinct b) as f32 ----
    if (t < 320) {
        int i = t >> 6, ch = t & 63;
        int b = b_lo + i; if (b > BB - 1) b = BB - 1;
        int grow = ann[2 * b];
        short8v rv = *(const short8v*)(femb + (long)grow * JJ + ch * 8);
        float4 lo, hi;
        lo.x = bfraw2f((unsigned short)rv[0]); lo.y = bfraw2f((unsigned short)rv[1]);
        lo.z = bfraw2f((unsigned short)rv[2]); lo.w = bfraw2f((unsigned short)rv[3]);
        hi.x = bfraw2f((unsigned short)rv[4]); hi.y = bfraw2f((unsigned short)rv[5]);
        hi.z = bfraw2f((unsigned short)rv[6]); hi.w = bfraw2f((unsigned short)rv[7]);
        *(float4*)(fl + i * 512 + ch * 8)     = lo;
        *(float4*)(fl + i * 512 + ch * 8 + 4) = hi;
    }
    // ---- stage w_fc ----
    wl[t] = w_fc[t];
    wl[t + 256] = w_fc[t + 256];

    // ---- per-row-slot metadata ----
    float vm[8]; int selb = 0; int br_[2];
#pragma unroll
    for (int mt = 0; mt < 2; ++mt) {
        int base = m0 + wm * 32 + mt * 16 + lq * 4;
        int br0 = base / SS - b_lo;
        br_[mt] = br0;
#pragma unroll
        for (int reg = 0; reg < 4; ++reg) {
            int m = base + reg;
            int slot = mt * 4 + reg;
            if (m / SS - b_lo != br0) selb |= (1 << slot);
            vm[slot] = valid[m];
        }
    }
    __syncthreads();

    // ---- A fragments -> registers (80 VGPR) ----
    short8v areg[2][10];
#pragma unroll
    for (int mt = 0; mt < 2; ++mt) {
        int r = wm * 32 + mt * 16 + li;
#pragma unroll
        for (int kt = 0; kt < 10; ++kt)
            areg[mt][kt] = *(const short8v*)(buf + r * RBY + kt * 64 + lq * 16);
    }
    __syncthreads();   // all waves done with A-stage; region becomes B dbuf

    // ---- stage B tile 0 into buf half 0 (1312 chunks of 16B, 328 per wave) ----
    {
        const char* gB = (const char*)Wsb;
        const int wb = w * 328;
#pragma unroll
        for (int i = 0; i < 5; ++i)
            gload16(gB + (long)(wb + i * 64 + lane) * 16, buf + (wb + i * 64) * 16);
        if (lane < 8)
            gload16(gB + (long)(wb + 320 + lane) * 16, buf + (wb + 320) * 16);
    }
    float sp2[8] = {0.f, 0.f, 0.f, 0.f, 0.f, 0.f, 0.f, 0.f};
    __syncthreads();   // drains vmcnt: tile 0 visible

    const int fragoff = (wn * 16 + li) * RBY + lq * 16;

    for (int jt = 0; jt < 16; ++jt) {
        // ---- prefetch next tile into the other buffer (overlaps compute) ----
        if (jt < 15) {
            const char* gB = (const char*)Wsb + (long)(jt + 1) * BT2;
            char* nb = buf + ((jt + 1) & 1) * BT2;
            const int wb = w * 328;
#pragma unroll
            for (int i = 0; i < 5; ++i)
                gload16(gB + (long)(wb + i * 64 + lane) * 16, nb + (wb + i * 64) * 16);
            if (lane < 8)
                gload16(gB + (long)(wb + 320 + lane) * 16, nb + (wb + 320) * 16);
        }

        // ---- 20 MFMA over K=320 (both m-frags share each B read) ----
        const char* cb = buf + (jt & 1) * BT2 + fragoff;
        float4v acc0 = {0.f, 0.f, 0.f, 0.f}, acc1 = {0.f, 0.f, 0.f, 0.f};
#pragma unroll
        for (int kt = 0; kt < 10; ++kt) {
            short8v b0 = *(const short8v*)(cb + kt * 64);
            acc0 = __builtin_amdgcn_mfma_f32_16x16x32_bf16(areg[0][kt], b0, acc0, 0, 0, 0);
            acc1 = __builtin_amdgcn_mfma_f32_16x16x32_bf16(areg[1][kt], b0, acc1, 0, 0, 0);
        }

        // ---- epilogue slice: sp2 += w_fc * rcp(exp(2x)+1) ----
        {
            int col = jt * 32 + wn * 16 + li;
            float wf = wl[col];
#pragma unroll
            for (int mt = 0; mt < 2; ++mt) {
                int br = br_[mt];
                int br1 = (br < 4) ? br + 1 : 4;
                float f0 = fl[br * 512 + col];
                float f1 = fl[br1 * 512 + col];
                float4v a = (mt == 0) ? acc0 : acc1;
#pragma unroll
                for (int reg = 0; reg < 4; ++reg) {
                    int slot = mt * 4 + reg;
                    float fv = ((selb >> slot) & 1) ? f1 : f0;
                    float x = a[reg] + vm[slot] * fv;
                    float e = __expf(2.f * x);
                    float r = __builtin_amdgcn_rcpf(e + 1.f);
                    sp2[slot] += wf * r;
                }
            }
        }
        __syncthreads();   // reads of cur done + prefetch drained
    }

    // ---- reduce across the 16 li lanes per row-slot ----
#pragma unroll
    for (int slot = 0; slot < 8; ++slot) {
        float v = sp2[slot];
        v += __shfl_xor(v, 1); v += __shfl_xor(v, 2);
        v += __shfl_xor(v, 4); v += __shfl_xor(v, 8);
        sp2[slot] = v;
    }
    float* red = (float*)smem;     // buf dead now
    if (li == 0) {
#pragma unroll
        for (int mt = 0; mt < 2; ++mt)
#pragma unroll
            for (int reg = 0; reg < 4; ++reg)
                red[wn * 64 + wm * 32 + mt * 16 + lq * 4 + reg] = sp2[mt * 4 + reg];
    }
    __syncthreads();
    if (t < 64)
        scores[m0 + t] = b_fc[0] + sumwf[0] - 2.f * (red[t] + red[64 + t]);
}

// ---------------- kernel 3: softmax + mask + renorm + weighted sum -------------
__global__ __launch_bounds__(256) void k3_out(const float* __restrict__ scores,
                                              const float* __restrict__ nonzero,
                                              const float* __restrict__ embedded,
                                              float* __restrict__ out) {
    __shared__ float wgt[3][SS];
    const int b0 = blockIdx.x * 3;
    const int t = threadIdx.x;
    if (t < 3) {
        int b = b0 + t;
        if (b < BB) {
            float sc[SS], nz[SS];
            float mx = -1e30f;
            for (int s = 0; s < SS; ++s) {
                sc[s] = scores[b * SS + s];
                nz[s] = nonzero[b * SS + s];
                mx = fmaxf(mx, sc[s]);
            }
            float den = 0.f, e[SS];
            for (int s = 0; s < SS; ++s) { e[s] = nz[s] * __expf(sc[s] - mx); den += e[s]; }
            float inv = 1.f / den;
            for (int s = 0; s < SS; ++s) wgt[t][s] = e[s] * inv;
        }
    }
    __syncthreads();
    if (t < 225) {
        int r = t / 75, q = t - r * 75;
        int b = b0 + r;
        if (b < BB) {
            float4 a; a.x = a.y = a.z = a.w = 0.f;
#pragma unroll
            for (int s = 0; s < SS; ++s) {
                float4 e = *(const float4*)(embedded + ((long)b * SS + s) * DD + q * 4);
                float ww = wgt[r][s];
                a.x += ww * e.x; a.y += ww * e.y; a.z += ww * e.z; a.w += ww * e.w;
            }
            *(float4*)(out + (long)b * DD + q * 4) = a;
        }
    }
}

extern "C" void kernel_launch(void* const* d_in, const int* in_sizes, int n_in,
                              void* d_out, int out_size, void* d_ws, size_t ws_size,
                              hipStream_t stream) {
    const float* context  = (const float*)d_in[0];
    const float* embedded = (const float*)d_in[1];
    const int*   labels   = (const int*)d_in[2];
    const float* guide    = (const float*)d_in[3];
    const int*   ann      = (const int*)d_in[4];
    const float* W_sent   = (const float*)d_in[5];
    const float* b_sent   = (const float*)d_in[6];
    const float* W_emb    = (const float*)d_in[7];
    const float* b_emb    = (const float*)d_in[8];
    const float* w_fc     = (const float*)d_in[9];
    const float* b_fc     = (const float*)d_in[10];
    float* out = (float*)d_out;

    char* w = (char*)d_ws;
    __hip_bfloat16* femb = (__hip_bfloat16*)(w);               // 1024*512*2 = 1048576
    float* valid         = (float*)(w + 1048576);              // 655360
    float* nonzero       = (float*)(w + 1703936);              // 655360
    float* scores        = (float*)(w + 2359296);              // 655360
    __hip_bfloat16* Wsb  = (__hip_bfloat16*)(w + 3014656);     // 512*328*2 = 335872
    __hip_bfloat16* Web  = (__hip_bfloat16*)(w + 3350528);     // 512*2112*2= 2162688
    __hip_bfloat16* Gb   = (__hip_bfloat16*)(w + 5513216);     // 1000*2112*2=4224000
    float* sums          = (float*)(w + 9737216);              // 4
    // total 9737220 bytes

    hipLaunchKernelGGL(kc_prep_wsb, dim3((JJ * KP + 255) / 256), dim3(256), 0, stream,
                       W_sent, b_sent, b_emb, Wsb);
    hipLaunchKernelGGL(kc_pad2, dim3((int)((1512L * 2112 + 255) / 256)), dim3(256), 0, stream,
                       W_emb, guide, Web, Gb);
    hipLaunchKernelGGL(kS_sumwf, dim3(1), dim3(512), 0, stream, w_fc, sums);
    hipLaunchKernelGGL(k0_valid, dim3(BB / 256), dim3(256), 0, stream,
                       labels, valid, nonzero);
    hipLaunchKernelGGL(k1_femb_mfma, dim3(16, JJ / 64), dim3(256), 0, stream,
                       Gb, Web, b_emb, femb);
    hipLaunchKernelGGL(k2_scores_mfma, dim3((BB * SS) / 64), dim3(256), 0, stream,
                       context, Wsb, w_fc, b_fc, sums, femb, ann, valid, scores);
    hipLaunchKernelGGL(k3_out, dim3((BB + 2) / 3), dim3(256), 0, stream,
                       scores, nonzero, embedded, out);
}